// Round 2
// baseline (268.872 us; speedup 1.0000x reference)
//
#include <hip/hip_runtime.h>

typedef __attribute__((ext_vector_type(8))) short short8;   // 8 bf16 = 4 VGPRs
typedef __attribute__((ext_vector_type(4))) float float4v;  // 4 fp32

static __device__ inline short f2bf(float f) {
    union { float f; unsigned u; } v; v.f = f;
    unsigned u = v.u;
    u += 0x7fffu + ((u >> 16) & 1u);   // round-to-nearest-even
    return (short)(u >> 16);
}

// Setup: Wt[n][k] = W[k][n] in bf16, row-major stride 128, written to d_ws.
// W[k][n] = [[cos, sin], [-sin, cos]] (cos/sin symmetric 64x64, scaled 1/64).
// 64 blocks x 256 thr = 16384 threads, one element each.
__global__ __launch_bounds__(256)
void build_wt(const float* __restrict__ cosk, const float* __restrict__ sink,
              short* __restrict__ wt)
{
    const int idx = blockIdx.x * 256 + threadIdx.x;  // 0..16383
    const int n = idx >> 7, k = idx & 127;
    const int nn = n & 63, km = k & 63;
    float v;
    if (n < 64) v = (k < 64) ? cosk[n * 64 + k] : -sink[n * 64 + km];
    else        v = (k < 64) ? sink[nn * 64 + k] : cosk[nn * 64 + km];
    wt[idx] = f2bf(v);
}

// Main: out[b,n'] = sum_k A[b,k] * W[k,n'].  One wave = 32 batches
// (two 16-batch N-subtiles of 16x16x32 MFMA, weights on the M side).
// Operand-swapped MFMA: D = Wt_tile . X_tile  =>  lane (q,m) holds
// out[b0+u*16+m][nt*16 + q*4 + r] for r=0..3  => contiguous float4 store.
__global__ __launch_bounds__(256, 2)
void ofdm_idft_kernel(const float* __restrict__ eq,
                      const short* __restrict__ wt,
                      float* __restrict__ out)
{
    const int lane = threadIdx.x & 63;
    const int wave = threadIdx.x >> 6;
    const int m = lane & 15;   // A row (n' within tile) / B col (batch) index
    const int q = lane >> 4;   // quad: k-offset for frags, row-group for D
    const int b0 = (blockIdx.x * 4 + wave) * 32;

    const unsigned long long PMASK =
        (1ull << 11) | (1ull << 25) | (1ull << 39) | (1ull << 53);

    // ---- X preload: 16 independent dwordx4, issued back-to-back ----
    float4v x[16];
    const float* a0 = eq + (size_t)(b0 + m) * 128 + q * 8;
    #pragma unroll
    for (int u = 0; u < 2; ++u) {
        const float* a = a0 + u * (16 * 128);
        #pragma unroll
        for (int kk = 0; kk < 4; ++kk) {
            x[u * 8 + kk * 2 + 0] = *(const float4v*)(a + kk * 32);
            x[u * 8 + kk * 2 + 1] = *(const float4v*)(a + kk * 32 + 4);
        }
    }

    // ---- cvt + pilot: X[b=m][k = kk*32 + q*8 + j] (B-operand frags) ----
    short8 xfr[2][4];
    #pragma unroll
    for (int u = 0; u < 2; ++u) {
        #pragma unroll
        for (int kk = 0; kk < 4; ++kk) {
            short8 f;
            #pragma unroll
            for (int j = 0; j < 8; ++j) {
                float xv = (j < 4) ? x[u * 8 + kk * 2][j] : x[u * 8 + kk * 2 + 1][j - 4];
                const int k = kk * 32 + q * 8 + j;
                if ((PMASK >> (k & 63)) & 1ull)
                    xv = (k < 64) ? 1.0f : 0.0f;   // pilot: real->1, imag->0
                f[j] = f2bf(xv);
            }
            xfr[u][kk] = f;
        }
    }

    float4v acc[2][8];
    #pragma unroll
    for (int u = 0; u < 2; ++u)
        #pragma unroll
        for (int nt = 0; nt < 8; ++nt)
            acc[u][nt] = (float4v){0.f, 0.f, 0.f, 0.f};

    // ---- MFMA: Wt frags from L2 (hot per XCD) go on the M side ----
    #pragma unroll
    for (int kk = 0; kk < 4; ++kk) {
        short8 wfr[8];
        #pragma unroll
        for (int nt = 0; nt < 8; ++nt)
            wfr[nt] = *(const short8*)(wt + (nt * 16 + m) * 128 + kk * 32 + q * 8);
        #pragma unroll
        for (int nt = 0; nt < 8; ++nt) {
            acc[0][nt] = __builtin_amdgcn_mfma_f32_16x16x32_bf16(
                wfr[nt], xfr[0][kk], acc[0][nt], 0, 0, 0);
            acc[1][nt] = __builtin_amdgcn_mfma_f32_16x16x32_bf16(
                wfr[nt], xfr[1][kk], acc[1][nt], 0, 0, 0);
        }
    }

    // ---- Store: lane (q,m) owns out[b0+u*16+m][nt*16+q*4 .. +3] ----
    // 16 x global_store_dwordx4 (nontemporal: output is never re-read,
    // keep L2/L3 for the input stream). Each instr covers 16 full 64B segs.
    #pragma unroll
    for (int u = 0; u < 2; ++u) {
        float* ob = out + (size_t)(b0 + u * 16 + m) * 128 + q * 4;
        #pragma unroll
        for (int nt = 0; nt < 8; ++nt)
            __builtin_nontemporal_store(acc[u][nt], (float4v*)(ob + nt * 16));
    }
}

extern "C" void kernel_launch(void* const* d_in, const int* in_sizes, int n_in,
                              void* d_out, int out_size, void* d_ws, size_t ws_size,
                              hipStream_t stream) {
    const float* eq   = (const float*)d_in[0];
    const float* cosk = (const float*)d_in[1];
    const float* sink = (const float*)d_in[2];
    float* out = (float*)d_out;
    short* wt  = (short*)d_ws;   // 128*128*2 = 32768 B of workspace

    hipLaunchKernelGGL(build_wt, dim3(64), dim3(256), 0, stream, cosk, sink, wt);
    // 2048 blocks * 4 waves * 32 batches = 262144, exact cover
    hipLaunchKernelGGL(ofdm_idft_kernel, dim3(2048), dim3(256), 0, stream,
                       eq, wt, out);
}

// Round 3
// 264.362 us; speedup vs baseline: 1.0171x; 1.0171x over previous
//
#include <hip/hip_runtime.h>

typedef __attribute__((ext_vector_type(8))) short short8;   // 8 bf16 = 4 VGPRs
typedef __attribute__((ext_vector_type(4))) float float4v;  // 4 fp32

static __device__ inline short f2bf(float f) {
    union { float f; unsigned u; } v; v.f = f;
    unsigned u = v.u;
    u += 0x7fffu + ((u >> 16) & 1u);   // round-to-nearest-even
    return (short)(u >> 16);
}

// Setup: Wt[n][k] = W[k][n] in bf16, row-major stride 128, written to d_ws.
// W[k][n] = [[cos, sin], [-sin, cos]] (cos/sin symmetric 64x64, scaled 1/64).
__global__ __launch_bounds__(256)
void build_wt(const float* __restrict__ cosk, const float* __restrict__ sink,
              short* __restrict__ wt)
{
    const int idx = blockIdx.x * 256 + threadIdx.x;  // 0..16383
    const int n = idx >> 7, k = idx & 127;
    const int nn = n & 63, km = k & 63;
    float v;
    if (n < 64) v = (k < 64) ? cosk[n * 64 + k] : -sink[n * 64 + km];
    else        v = (k < 64) ? sink[nn * 64 + k] : cosk[nn * 64 + km];
    wt[idx] = f2bf(v);
}

// Main: out[b,n'] = sum_k A[b,k] * W[k,n'].  Persistent waves: 2048 waves,
// each does NT=4 tiles of 32 batches (grid-stride 2048 tiles), software-
// pipelined: after converting tile it to bf16 frags, the same xb registers
// are refilled with tile it+1's loads, which stay in flight across the
// MFMA + store of tile it. Operand-swapped MFMA (weights on M) so lane
// (q,m) holds out[b0+u*16+m][nt*16+q*4 .. +3] => contiguous dwordx4 store.
__global__ __launch_bounds__(256, 2)
void ofdm_idft_kernel(const float* __restrict__ eq,
                      const short* __restrict__ wt,
                      float* __restrict__ out)
{
    const int lane = threadIdx.x & 63;
    const int wave = threadIdx.x >> 6;
    const int m = lane & 15;   // A row (n' within tile) / B col (batch) index
    const int q = lane >> 4;   // quad: k-offset for frags, row-group for D
    const int wg = blockIdx.x * 4 + wave;   // 0..2047

    const unsigned long long PMASK =
        (1ull << 11) | (1ull << 25) | (1ull << 39) | (1ull << 53);

#define ISSUE_TILE(TILE)                                                     \
    {                                                                        \
        const float* a0 = eq + (size_t)((TILE) * 32 + m) * 128 + q * 8;      \
        _Pragma("unroll")                                                    \
        for (int u = 0; u < 2; ++u) {                                        \
            const float* a = a0 + u * (16 * 128);                            \
            _Pragma("unroll")                                                \
            for (int kk = 0; kk < 4; ++kk) {                                 \
                xb[u * 8 + kk * 2 + 0] = *(const float4v*)(a + kk * 32);     \
                xb[u * 8 + kk * 2 + 1] = *(const float4v*)(a + kk * 32 + 4); \
            }                                                                \
        }                                                                    \
    }

    float4v xb[16];
    ISSUE_TILE(wg);   // tile 0 loads in flight

    #pragma unroll
    for (int it = 0; it < 4; ++it) {
        const int b0 = (wg + it * 2048) * 32;

        // ---- cvt + pilot: waits on xb loads, then xb is dead ----
        short8 xfr[2][4];
        #pragma unroll
        for (int u = 0; u < 2; ++u) {
            #pragma unroll
            for (int kk = 0; kk < 4; ++kk) {
                short8 f;
                #pragma unroll
                for (int j = 0; j < 8; ++j) {
                    float xv = (j < 4) ? xb[u * 8 + kk * 2][j]
                                       : xb[u * 8 + kk * 2 + 1][j - 4];
                    const int k = kk * 32 + q * 8 + j;
                    if ((PMASK >> (k & 63)) & 1ull)
                        xv = (k < 64) ? 1.0f : 0.0f;   // pilot: real->1, imag->0
                    f[j] = f2bf(xv);
                }
                xfr[u][kk] = f;
            }
        }

        // ---- prefetch next tile: in flight across MFMA + store below ----
        if (it < 3) {
            ISSUE_TILE(wg + (it + 1) * 2048);
        }

        float4v acc[2][8];
        #pragma unroll
        for (int u = 0; u < 2; ++u)
            #pragma unroll
            for (int nt = 0; nt < 8; ++nt)
                acc[u][nt] = (float4v){0.f, 0.f, 0.f, 0.f};

        // ---- MFMA: Wt frags (same addresses every tile -> L1/L2-hot) ----
        #pragma unroll
        for (int kk = 0; kk < 4; ++kk) {
            short8 wfr[8];
            #pragma unroll
            for (int nt = 0; nt < 8; ++nt)
                wfr[nt] = *(const short8*)(wt + (nt * 16 + m) * 128 + kk * 32 + q * 8);
            #pragma unroll
            for (int nt = 0; nt < 8; ++nt) {
                acc[0][nt] = __builtin_amdgcn_mfma_f32_16x16x32_bf16(
                    wfr[nt], xfr[0][kk], acc[0][nt], 0, 0, 0);
                acc[1][nt] = __builtin_amdgcn_mfma_f32_16x16x32_bf16(
                    wfr[nt], xfr[1][kk], acc[1][nt], 0, 0, 0);
            }
        }

        // ---- store: plain dwordx4 (L2 write-combines; nt was a regression) ----
        #pragma unroll
        for (int u = 0; u < 2; ++u) {
            float* ob = out + (size_t)(b0 + u * 16 + m) * 128 + q * 4;
            #pragma unroll
            for (int nt = 0; nt < 8; ++nt)
                *(float4v*)(ob + nt * 16) = acc[u][nt];
        }
    }
#undef ISSUE_TILE
}

extern "C" void kernel_launch(void* const* d_in, const int* in_sizes, int n_in,
                              void* d_out, int out_size, void* d_ws, size_t ws_size,
                              hipStream_t stream) {
    const float* eq   = (const float*)d_in[0];
    const float* cosk = (const float*)d_in[1];
    const float* sink = (const float*)d_in[2];
    float* out = (float*)d_out;
    short* wt  = (short*)d_ws;   // 128*128*2 = 32768 B of workspace

    hipLaunchKernelGGL(build_wt, dim3(64), dim3(256), 0, stream, cosk, sink, wt);
    // 512 blocks * 4 waves * 4 tiles * 32 batches = 262144, exact cover
    hipLaunchKernelGGL(ofdm_idft_kernel, dim3(512), dim3(256), 0, stream,
                       eq, wt, out);
}